// Round 20
// baseline (131.355 us; speedup 1.0000x reference)
//
#include <hip/hip_runtime.h>

typedef __attribute__((ext_vector_type(8))) short short8;
typedef __attribute__((ext_vector_type(4))) float float4v;
typedef __attribute__((ext_vector_type(4))) float floatx4;
typedef __attribute__((ext_vector_type(4))) unsigned short ushort4v;

#define DEV static __device__ __forceinline__
#define MFMA __builtin_amdgcn_mfma_f32_16x16x32_bf16

DEV unsigned short f2bf(float f){
  unsigned u = __builtin_bit_cast(unsigned, f);
  unsigned r = u + 0x7FFFu + ((u >> 16) & 1u);
  return (unsigned short)(r >> 16);
}
DEV float bf2f(unsigned short h){
  unsigned u = ((unsigned)h) << 16;
  return __builtin_bit_cast(float, u);
}
DEV float softplus_f(float x){
  if (x > 20.f) return x;
  return log1pf(expf(x));
}

DEV void gload16(const void* g, void* l){
  __builtin_amdgcn_global_load_lds(
      (const __attribute__((address_space(1))) unsigned int*)g,
      (__attribute__((address_space(3))) unsigned int*)l, 16, 0, 0);
}

// ---------------------------------------------------------------------------
// Merged prep (R13-proven, byte-identical).
__global__ __launch_bounds__(256) void k_prep(
    const float* __restrict__ freq_raw, const float* __restrict__ pool_raw,
    const float* __restrict__ x,
    const float* __restrict__ Wq, const float* __restrict__ Wk,
    const float* __restrict__ Wv, const float* __restrict__ Wo,
    unsigned short* __restrict__ wq_h, unsigned short* __restrict__ wq_l,
    unsigned short* __restrict__ wk_h, unsigned short* __restrict__ wk_l,
    unsigned short* __restrict__ wv_b, unsigned short* __restrict__ wo_b,
    unsigned short* __restrict__ xh, unsigned short* __restrict__ xl){
  int g = blockIdx.x;
  int tid = threadIdx.x;
  if (g < 1024){
    __shared__ float red[256];
    int n = g;
    float s = 0.f;
    for (int j = tid; j < 1024; j += 256)
      if (j >= n) s += softplus_f(freq_raw[j]);
    red[tid] = s;
    __syncthreads();
    for (int off = 128; off > 0; off >>= 1){
      if (tid < off) red[tid] += red[tid + off];
      __syncthreads();
    }
    float f = red[0] * 0.125f;
    float p0 = softplus_f((pool_raw[0] + pool_raw[2]) * 0.5f);
    float p1 = softplus_f(pool_raw[1]);
    float p2 = p0;

    int k4 = tid << 2;
    int o = n * 1024 + k4;
    float4v q4 = *(const float4v*)(Wq + o);
    float4v k0v = *(const float4v*)(Wk + o);
    float4v km = {0.f,0.f,0.f,0.f}, kp = {0.f,0.f,0.f,0.f};
    if (n > 0)    km = *(const float4v*)(Wk + o - 1024);
    if (n < 1023) kp = *(const float4v*)(Wk + o + 1024);
    float4v v4 = *(const float4v*)(Wv + o);
    float4v o4 = *(const float4v*)(Wo + o);
    ushort4v qh, ql, kh, kl, vb, ob;
    for (int j = 0; j < 4; j++){
      float wq_ = f * q4[j];
      unsigned short h = f2bf(wq_);
      qh[j] = h; ql[j] = f2bf(wq_ - bf2f(h));
      float wk_ = p0 * km[j] + p1 * k0v[j] + p2 * kp[j];
      h = f2bf(wk_);
      kh[j] = h; kl[j] = f2bf(wk_ - bf2f(h));
      vb[j] = f2bf(v4[j]);
      ob[j] = f2bf(o4[j]);
    }
    *(ushort4v*)(wq_h + o) = qh; *(ushort4v*)(wq_l + o) = ql;
    *(ushort4v*)(wk_h + o) = kh; *(ushort4v*)(wk_l + o) = kl;
    *(ushort4v*)(wv_b + o) = vb; *(ushort4v*)(wo_b + o) = ob;
  } else {
    int idx = (g - 1024) * 256 + tid;
    int o = idx * 4;
    float4v v = *(const float4v*)(x + o);
    ushort4v h4, l4;
    for (int j = 0; j < 4; j++){
      unsigned short h = f2bf(v[j]);
      h4[j] = h; l4[j] = f2bf(v[j] - bf2f(h));
    }
    *(ushort4v*)(xh + o) = h4;
    *(ushort4v*)(xl + o) = l4;
  }
}

// ---------------------------------------------------------------------------
// Fused Q+K+V projection GEMM (R12/R13/R19-proven, byte-identical).
__global__ __launch_bounds__(256) void k_qkv(
    const unsigned short* __restrict__ Ah, const unsigned short* __restrict__ Al,
    const unsigned short* __restrict__ Bqh, const unsigned short* __restrict__ Bql,
    const unsigned short* __restrict__ Bkh, const unsigned short* __restrict__ Bkl,
    const unsigned short* __restrict__ Bvh,
    unsigned short* __restrict__ qh_o, unsigned short* __restrict__ ql_o,
    unsigned short* __restrict__ kh_o, unsigned short* __restrict__ kl_o,
    unsigned short* __restrict__ vt_o){
  __shared__ unsigned short lds[2][18432];
  int tid = threadIdx.x;
  int w = tid >> 6, l = tid & 63, lg = l >> 4, lr = l & 15;
  int wr = w >> 1, wc = w & 1;
  int g = blockIdx.x;
  int mblk = (g & 7) * 4 + ((g >> 3) & 3);
  int nblk = g >> 5;
  int m0 = mblk * 128, n0 = nblk * 64;

  auto stage = [&](int kt, int bufi){
    unsigned short* buf = lds[bufi];
    for (int rep = 0; rep < 2; rep++){
      int idx = rep * 256 + tid;
      int r = idx >> 2, c = idx & 3;
      int cs = (c ^ ((r >> 1) & 3)) * 8;
      int srcA = (m0 + r) * 1024 + kt + cs;
      unsigned short* dst = buf + rep * 2048 + w * 512;
      gload16(Ah + srcA, dst);
      gload16(Al + srcA, dst + 4096);
    }
    {
      int r = tid >> 2, c = tid & 3;
      int cs = (c ^ ((r >> 1) & 3)) * 8;
      int srcB = (n0 + r) * 1024 + kt + cs;
      unsigned short* dst = buf + 8192 + w * 512;
      gload16(Bqh + srcB, dst);
      gload16(Bql + srcB, dst + 2048);
      gload16(Bkh + srcB, dst + 4096);
      gload16(Bkl + srcB, dst + 6144);
      gload16(Bvh + srcB, dst + 8192);
    }
  };

  floatx4 aq[4][2] = {}, ak[4][2] = {}, av[4][2] = {};
  stage(0, 0);
  __syncthreads();
  int cur = 0;
  for (int kt = 0; kt < 1024; kt += 32){
    if (kt + 32 < 1024) stage(kt + 32, cur ^ 1);
    const unsigned short* buf = lds[cur];
    short8 a_h[4], a_l[4], bq_h[2], bq_l[2], bk_h[2], bk_l[2], bv_h[2];
    #pragma unroll
    for (int ms = 0; ms < 4; ms++){
      int r = wr * 64 + ms * 16 + lr;
      int off = r * 32 + ((lg ^ ((r >> 1) & 3)) * 8);
      a_h[ms] = *(const short8*)(buf + off);
      a_l[ms] = *(const short8*)(buf + 4096 + off);
    }
    #pragma unroll
    for (int ns = 0; ns < 2; ns++){
      int r = wc * 32 + ns * 16 + lr;
      int off = r * 32 + ((lg ^ ((r >> 1) & 3)) * 8);
      bq_h[ns] = *(const short8*)(buf + 8192 + off);
      bq_l[ns] = *(const short8*)(buf + 10240 + off);
      bk_h[ns] = *(const short8*)(buf + 12288 + off);
      bk_l[ns] = *(const short8*)(buf + 14336 + off);
      bv_h[ns] = *(const short8*)(buf + 16384 + off);
    }
    #pragma unroll
    for (int ms = 0; ms < 4; ms++)
      #pragma unroll
      for (int ns = 0; ns < 2; ns++){
        aq[ms][ns] = MFMA(a_h[ms], bq_h[ns], aq[ms][ns], 0, 0, 0);
        aq[ms][ns] = MFMA(a_h[ms], bq_l[ns], aq[ms][ns], 0, 0, 0);
        aq[ms][ns] = MFMA(a_l[ms], bq_h[ns], aq[ms][ns], 0, 0, 0);
        ak[ms][ns] = MFMA(a_h[ms], bk_h[ns], ak[ms][ns], 0, 0, 0);
        ak[ms][ns] = MFMA(a_h[ms], bk_l[ns], ak[ms][ns], 0, 0, 0);
        ak[ms][ns] = MFMA(a_l[ms], bk_h[ns], ak[ms][ns], 0, 0, 0);
        av[ms][ns] = MFMA(a_h[ms], bv_h[ns], av[ms][ns], 0, 0, 0);
      }
    __syncthreads();
    cur ^= 1;
  }
  for (int ms = 0; ms < 4; ms++)
    for (int ns = 0; ns < 2; ns++){
      int mrow = m0 + wr * 64 + ms * 16 + lg * 4;
      int ncol = n0 + wc * 32 + ns * 16 + lr;
      for (int rr = 0; rr < 4; rr++){
        int o = (mrow + rr) * 1024 + ncol;
        float v = aq[ms][ns][rr];
        unsigned short hh = f2bf(v);
        qh_o[o] = hh; ql_o[o] = f2bf(v - bf2f(hh));
        v = ak[ms][ns][rr];
        hh = f2bf(v);
        kh_o[o] = hh; kl_o[o] = f2bf(v - bf2f(hh));
      }
      int tb = m0 + wr * 64;
      int bq = tb >> 10, sg = (tb >> 6) & 15;
      int P0 = ((ms >> 1) << 5) | (lg << 3) | ((ms & 1) << 2);
      ushort4v v4;
      for (int rr = 0; rr < 4; rr++) v4[rr] = f2bf(av[ms][ns][rr]);
      *(ushort4v*)(vt_o + (ncol * 4 + bq) * 1024 + sg * 64 + P0) = v4;
    }
}

// ---------------------------------------------------------------------------
// Plain GEMM (final output projection), R13-proven 3-ring + counted vmcnt.
template<int OUT>
__global__ __launch_bounds__(256) void k_gemm(
    const unsigned short* __restrict__ Ah, const unsigned short* __restrict__ Bh,
    void* __restrict__ out0, int M, int N, int K){
  constexpr int BUFN = 6144;
  __shared__ unsigned short lds[3 * BUFN];
  int tid = threadIdx.x;
  int w = tid >> 6, l = tid & 63, lg = l >> 4, lr = l & 15;
  int wr = w >> 1, wc = w & 1;
  int n0 = blockIdx.x * 128, m0 = blockIdx.y * 64;

  auto stage = [&](int kt, int bufi){
    unsigned short* buf = lds + bufi * BUFN;
    { int r = tid >> 2, c = tid & 3;
      int src = (m0 + r) * K + kt + (c ^ ((r >> 1) & 3)) * 8;
      gload16(Ah + src, buf + w * 512); }
    for (int rep = 0; rep < 2; rep++){
      int idx = rep * 256 + tid;
      int r = idx >> 2, c = idx & 3;
      int src = (n0 + r) * K + kt + (c ^ ((r >> 1) & 3)) * 8;
      gload16(Bh + src, buf + 2048 + rep * 2048 + w * 512);
    }
  };

  floatx4 acc[2][4] = {};
  int nT = K >> 5;
  stage(0, 0);
  stage(32, 1);
  for (int t = 0; t < nT; ++t){
    if (t == nT - 1) asm volatile("s_waitcnt vmcnt(0)" ::: "memory");
    else             asm volatile("s_waitcnt vmcnt(3)" ::: "memory");
    __builtin_amdgcn_sched_barrier(0);
    __builtin_amdgcn_s_barrier();
    __builtin_amdgcn_sched_barrier(0);
    if (t + 2 < nT) stage((t + 2) * 32, (t + 2) % 3);

    const unsigned short* buf = lds + (t % 3) * BUFN;
    short8 a_h[2], b_h[4];
    #pragma unroll
    for (int ms = 0; ms < 2; ms++){
      int r = wr * 32 + ms * 16 + lr;
      int off = r * 32 + ((lg ^ ((r >> 1) & 3)) * 8);
      a_h[ms] = *(const short8*)(buf + off);
    }
    #pragma unroll
    for (int ns = 0; ns < 4; ns++){
      int r = wc * 64 + ns * 16 + lr;
      int off = r * 32 + ((lg ^ ((r >> 1) & 3)) * 8);
      b_h[ns] = *(const short8*)(buf + 2048 + off);
    }
    #pragma unroll
    for (int ms = 0; ms < 2; ms++)
      #pragma unroll
      for (int ns = 0; ns < 4; ns++)
        acc[ms][ns] = MFMA(a_h[ms], b_h[ns], acc[ms][ns], 0, 0, 0);
  }
  for (int ms = 0; ms < 2; ms++)
    for (int ns = 0; ns < 4; ns++){
      int mrow = m0 + wr * 32 + ms * 16 + lg * 4;
      int ncol = n0 + wc * 64 + ns * 16 + lr;
      for (int rr = 0; rr < 4; rr++){
        float v = acc[ms][ns][rr];
        int o = (mrow + rr) * N + ncol;
        if constexpr (OUT == 2) ((float*)out0)[o] = v;
        else                    ((unsigned short*)out0)[o] = f2bf(v);
      }
    }
}

// ---------------------------------------------------------------------------
// Flash attention, swapped-operand, QBLK=128 (R14-passed body). Grid 512.
// Constant-sum qt pairing: qt = (g>>6 < 4) ? g>>6 : 11-(g>>6), so blocks g
// and g+256 (same CU under double-round-robin dispatch) carry qt and 7-qt --
// per-CU work is exactly 18 tile-units for every CU (and same bh -> shared
// K/V in L2). One K/V LDS read serves both q-fragments of each wave.
// Vt layout: [H][hd][B][S_kappa], addr = ((h*64+d)*4 + b)*1024 + s_phys.
__global__ __launch_bounds__(256) void k_attn(
    const unsigned short* __restrict__ Qh, const unsigned short* __restrict__ Ql,
    const unsigned short* __restrict__ Kh, const unsigned short* __restrict__ Kl,
    const unsigned short* __restrict__ Vt, unsigned short* __restrict__ Ob){
  __shared__ unsigned short s_k[2][12288];   // per buf: Kh 4096 | Kl 4096 | V 4096
  int tid = threadIdx.x;
  int w = tid >> 6, l = tid & 63, lg = l >> 4, lr = l & 15;
  int gx = blockIdx.x;
  int hi = gx >> 6;
  int qt = (hi < 4) ? hi : 11 - hi;          // pair (qt, 7-qt) per CU
  int bh = gx & 63;
  int b = bh >> 4, h = bh & 15;
  int q0 = qt * 128;
  int rowb = b * 1024;
  int qb[2] = { q0 + w * 16, q0 + 64 + w * 16 };

  auto stage = [&](int kt, int bufi){
    int k0 = kt * 64;
    unsigned short* buf = s_k[bufi];
    for (int rep = 0; rep < 2; rep++){
      int idx = rep * 256 + tid;
      int r = idx >> 3, c = idx & 7;
      int cs = c ^ (r & 7);
      int srcK = (rowb + k0 + r) * 1024 + h * 64 + cs * 8;
      int srcV = ((h * 64 + r) * 4 + b) * 1024 + k0 + cs * 8;
      unsigned short* dst = buf + rep * 2048 + w * 512;
      gload16(Kh + srcK, dst);
      gload16(Kl + srcK, dst + 4096);
      gload16(Vt + srcV, dst + 8192);
    }
  };

  // Q fragments (B-operand), two q-blocks per wave
  short8 fqh[2][2], fql[2][2];
  for (int qm = 0; qm < 2; qm++)
    for (int ds = 0; ds < 2; ds++){
      int off = (rowb + qb[qm] + lr) * 1024 + h * 64 + ds * 32 + lg * 8;
      fqh[qm][ds] = *(const short8*)(Qh + off);
      fql[qm][ds] = *(const short8*)(Ql + off);
    }

  floatx4 oT[2][4] = {};   // [qm][dsb]: col q = lr, row d = dsb*16+4lg+rr
  float m_[2], l_[2];
  m_[0] = m_[1] = -__builtin_inff();
  l_[0] = l_[1] = 0.f;

  int ntile = 2 * qt + 2;
  stage(0, 0);
  __syncthreads();
  int cur = 0;
  for (int kt = 0; kt < ntile; kt++){
    int k0 = kt * 64;
    if (kt + 1 < ntile) stage(kt + 1, cur ^ 1);
    const unsigned short* kb = s_k[cur];

    floatx4 sc[2][4];
    bool act0 = (kt < ntile - 1);            // qm0 fully masked on last tile
    #pragma unroll
    for (int qm = 0; qm < 2; qm++){
      if (qm == 0 && !act0) continue;
      #pragma unroll
      for (int s = 0; s < 4; s++) sc[qm][s] = floatx4{0.f,0.f,0.f,0.f};
      __builtin_amdgcn_s_setprio(1);
      for (int ds = 0; ds < 2; ds++)
        for (int s = 0; s < 4; s++){
          int r = s * 16 + lr;
          int off = r * 64 + (((ds * 4 + lg) ^ (r & 7)) * 8);
          short8 kh_f = *(const short8*)(kb + off);
          short8 kl_f = *(const short8*)(kb + 4096 + off);
          sc[qm][s] = MFMA(kh_f, fqh[qm][ds], sc[qm][s], 0, 0, 0);
          sc[qm][s] = MFMA(kl_f, fqh[qm][ds], sc[qm][s], 0, 0, 0);
          sc[qm][s] = MFMA(kh_f, fql[qm][ds], sc[qm][s], 0, 0, 0);
        }
      __builtin_amdgcn_s_setprio(0);

      bool diag = (qm == 0) ? (kt == ntile - 2) : (kt == ntile - 1);
      if (diag){
        int q = qb[qm] + lr;
        #pragma unroll
        for (int s = 0; s < 4; s++)
          #pragma unroll
          for (int rr = 0; rr < 4; rr++)
            if (k0 + s * 16 + 4 * lg + rr > q) sc[qm][s][rr] = -__builtin_inff();
      }

      float mx = sc[qm][0][0];
      #pragma unroll
      for (int s = 0; s < 4; s++)
        #pragma unroll
        for (int rr = 0; rr < 4; rr++) mx = fmaxf(mx, sc[qm][s][rr]);
      mx = fmaxf(mx, __shfl_xor(mx, 16));
      mx = fmaxf(mx, __shfl_xor(mx, 32));
      float mn = fmaxf(m_[qm], mx);
      float fac = __expf(m_[qm] - mn);
      m_[qm] = mn;
      float ps = 0.f;
      #pragma unroll
      for (int s = 0; s < 4; s++)
        #pragma unroll
        for (int rr = 0; rr < 4; rr++){
          float p = __expf(sc[qm][s][rr] - mn);
          sc[qm][s][rr] = p;
          ps += p;
        }
      ps += __shfl_xor(ps, 16);
      ps += __shfl_xor(ps, 32);
      l_[qm] = l_[qm] * fac + ps;
      #pragma unroll
      for (int dsb = 0; dsb < 4; dsb++) oT[qm][dsb] *= fac;
    }

    // PV: one V read serves both q-blocks
    __builtin_amdgcn_s_setprio(1);
    #pragma unroll
    for (int kk = 0; kk < 2; kk++){
      short8 pb[2];
      #pragma unroll
      for (int qm = 0; qm < 2; qm++){
        if (qm == 0 && !act0) continue;
        #pragma unroll
        for (int j = 0; j < 8; j++)
          pb[qm][j] = (short)f2bf(sc[qm][2 * kk + (j >> 2)][j & 3]);
      }
      #pragma unroll
      for (int dsb = 0; dsb < 4; dsb++){
        int rv = dsb * 16 + lr;
        int offv = rv * 64 + (((kk * 4 + lg) ^ (rv & 7)) * 8);
        short8 vb = *(const short8*)(kb + 8192 + offv);
        if (act0) oT[0][dsb] = MFMA(vb, pb[0], oT[0][dsb], 0, 0, 0);
        oT[1][dsb] = MFMA(vb, pb[1], oT[1][dsb], 0, 0, 0);
      }
    }
    __builtin_amdgcn_s_setprio(0);
    __syncthreads();
    cur ^= 1;
  }

  #pragma unroll
  for (int qm = 0; qm < 2; qm++){
    float inv = 1.f / l_[qm];
    int base = (rowb + qb[qm] + lr) * 1024 + h * 64;
    #pragma unroll
    for (int dsb = 0; dsb < 4; dsb++){
      ushort4v o4;
      #pragma unroll
      for (int rr = 0; rr < 4; rr++) o4[rr] = f2bf(oT[qm][dsb][rr] * inv);
      *(ushort4v*)(Ob + base + dsb * 16 + 4 * lg) = o4;
    }
  }
}

// ---------------------------------------------------------------------------
extern "C" void kernel_launch(void* const* d_in, const int* in_sizes, int n_in,
                              void* d_out, int out_size, void* d_ws, size_t ws_size,
                              hipStream_t stream){
  const float* x  = (const float*)d_in[0];
  const float* Wq = (const float*)d_in[1];
  const float* Wk = (const float*)d_in[2];
  const float* Wv = (const float*)d_in[3];
  const float* Wo = (const float*)d_in[4];
  const float* fr = (const float*)d_in[5];
  const float* pr = (const float*)d_in[6];

  char* ws = (char*)d_ws;
  size_t off = 0;
  auto alloc = [&](size_t bytes) -> char* {
    char* p = ws + off;
    off += (bytes + 255) & ~(size_t)255;
    return p;
  };
  const size_t WB = (size_t)1024 * 1024 * 2;
  unsigned short* wq_h = (unsigned short*)alloc(WB);
  unsigned short* wq_l = (unsigned short*)alloc(WB);
  unsigned short* wk_h = (unsigned short*)alloc(WB);
  unsigned short* wk_l = (unsigned short*)alloc(WB);
  unsigned short* wv_b = (unsigned short*)alloc(WB);
  unsigned short* wo_b = (unsigned short*)alloc(WB);
  const size_t XB = (size_t)4096 * 1024 * 2;
  unsigned short* x_h = (unsigned short*)alloc(XB);
  unsigned short* x_l = (unsigned short*)alloc(XB);
  unsigned short* q_h = (unsigned short*)alloc(XB);
  unsigned short* q_l = (unsigned short*)alloc(XB);
  unsigned short* k_h = (unsigned short*)alloc(XB);
  unsigned short* k_l = (unsigned short*)alloc(XB);
  unsigned short* vt  = (unsigned short*)alloc(XB);   // V^T [H*hd][B*S_kappa]
  unsigned short* o_b = x_l;   // alias: x_l dead after k_qkv

  k_prep<<<5120, 256, 0, stream>>>(fr, pr, x, Wq, Wk, Wv, Wo,
                                   wq_h, wq_l, wk_h, wk_l, wv_b, wo_b,
                                   x_h, x_l);
  k_qkv<<<512, 256, 0, stream>>>(x_h, x_l, wq_h, wq_l, wk_h, wk_l, wv_b,
                                 q_h, q_l, k_h, k_l, vt);
  k_attn<<<512, 256, 0, stream>>>(q_h, q_l, k_h, k_l, vt, o_b);
  dim3 ggo(8, 64);
  k_gemm<2><<<ggo, 256, 0, stream>>>(o_b, wo_b, d_out, 4096, 1024, 1024);
}

// Round 21
// 118.612 us; speedup vs baseline: 1.1074x; 1.1074x over previous
//
#include <hip/hip_runtime.h>

typedef __attribute__((ext_vector_type(8))) short short8;
typedef __attribute__((ext_vector_type(4))) float float4v;
typedef __attribute__((ext_vector_type(4))) float floatx4;
typedef __attribute__((ext_vector_type(4))) unsigned short ushort4v;

#define DEV static __device__ __forceinline__
#define MFMA __builtin_amdgcn_mfma_f32_16x16x32_bf16

DEV unsigned short f2bf(float f){
  unsigned u = __builtin_bit_cast(unsigned, f);
  unsigned r = u + 0x7FFFu + ((u >> 16) & 1u);
  return (unsigned short)(r >> 16);
}
DEV float bf2f(unsigned short h){
  unsigned u = ((unsigned)h) << 16;
  return __builtin_bit_cast(float, u);
}
DEV float softplus_f(float x){
  if (x > 20.f) return x;
  return log1pf(expf(x));
}

DEV void gload16(const void* g, void* l){
  __builtin_amdgcn_global_load_lds(
      (const __attribute__((address_space(1))) unsigned int*)g,
      (__attribute__((address_space(3))) unsigned int*)l, 16, 0, 0);
}

// ---------------------------------------------------------------------------
// Merged prep (R13-proven, byte-identical).
__global__ __launch_bounds__(256) void k_prep(
    const float* __restrict__ freq_raw, const float* __restrict__ pool_raw,
    const float* __restrict__ x,
    const float* __restrict__ Wq, const float* __restrict__ Wk,
    const float* __restrict__ Wv, const float* __restrict__ Wo,
    unsigned short* __restrict__ wq_h, unsigned short* __restrict__ wq_l,
    unsigned short* __restrict__ wk_h, unsigned short* __restrict__ wk_l,
    unsigned short* __restrict__ wv_b, unsigned short* __restrict__ wo_b,
    unsigned short* __restrict__ xh, unsigned short* __restrict__ xl){
  int g = blockIdx.x;
  int tid = threadIdx.x;
  if (g < 1024){
    __shared__ float red[256];
    int n = g;
    float s = 0.f;
    for (int j = tid; j < 1024; j += 256)
      if (j >= n) s += softplus_f(freq_raw[j]);
    red[tid] = s;
    __syncthreads();
    for (int off = 128; off > 0; off >>= 1){
      if (tid < off) red[tid] += red[tid + off];
      __syncthreads();
    }
    float f = red[0] * 0.125f;
    float p0 = softplus_f((pool_raw[0] + pool_raw[2]) * 0.5f);
    float p1 = softplus_f(pool_raw[1]);
    float p2 = p0;

    int k4 = tid << 2;
    int o = n * 1024 + k4;
    float4v q4 = *(const float4v*)(Wq + o);
    float4v k0v = *(const float4v*)(Wk + o);
    float4v km = {0.f,0.f,0.f,0.f}, kp = {0.f,0.f,0.f,0.f};
    if (n > 0)    km = *(const float4v*)(Wk + o - 1024);
    if (n < 1023) kp = *(const float4v*)(Wk + o + 1024);
    float4v v4 = *(const float4v*)(Wv + o);
    float4v o4 = *(const float4v*)(Wo + o);
    ushort4v qh, ql, kh, kl, vb, ob;
    for (int j = 0; j < 4; j++){
      float wq_ = f * q4[j];
      unsigned short h = f2bf(wq_);
      qh[j] = h; ql[j] = f2bf(wq_ - bf2f(h));
      float wk_ = p0 * km[j] + p1 * k0v[j] + p2 * kp[j];
      h = f2bf(wk_);
      kh[j] = h; kl[j] = f2bf(wk_ - bf2f(h));
      vb[j] = f2bf(v4[j]);
      ob[j] = f2bf(o4[j]);
    }
    *(ushort4v*)(wq_h + o) = qh; *(ushort4v*)(wq_l + o) = ql;
    *(ushort4v*)(wk_h + o) = kh; *(ushort4v*)(wk_l + o) = kl;
    *(ushort4v*)(wv_b + o) = vb; *(ushort4v*)(wo_b + o) = ob;
  } else {
    int idx = (g - 1024) * 256 + tid;
    int o = idx * 4;
    float4v v = *(const float4v*)(x + o);
    ushort4v h4, l4;
    for (int j = 0; j < 4; j++){
      unsigned short h = f2bf(v[j]);
      h4[j] = h; l4[j] = f2bf(v[j] - bf2f(h));
    }
    *(ushort4v*)(xh + o) = h4;
    *(ushort4v*)(xl + o) = l4;
  }
}

// ---------------------------------------------------------------------------
// Fused Q+K+V projection GEMM (R12/R13/R19-proven, byte-identical).
__global__ __launch_bounds__(256) void k_qkv(
    const unsigned short* __restrict__ Ah, const unsigned short* __restrict__ Al,
    const unsigned short* __restrict__ Bqh, const unsigned short* __restrict__ Bql,
    const unsigned short* __restrict__ Bkh, const unsigned short* __restrict__ Bkl,
    const unsigned short* __restrict__ Bvh,
    unsigned short* __restrict__ qh_o, unsigned short* __restrict__ ql_o,
    unsigned short* __restrict__ kh_o, unsigned short* __restrict__ kl_o,
    unsigned short* __restrict__ vt_o){
  __shared__ unsigned short lds[2][18432];
  int tid = threadIdx.x;
  int w = tid >> 6, l = tid & 63, lg = l >> 4, lr = l & 15;
  int wr = w >> 1, wc = w & 1;
  int g = blockIdx.x;
  int mblk = (g & 7) * 4 + ((g >> 3) & 3);
  int nblk = g >> 5;
  int m0 = mblk * 128, n0 = nblk * 64;

  auto stage = [&](int kt, int bufi){
    unsigned short* buf = lds[bufi];
    for (int rep = 0; rep < 2; rep++){
      int idx = rep * 256 + tid;
      int r = idx >> 2, c = idx & 3;
      int cs = (c ^ ((r >> 1) & 3)) * 8;
      int srcA = (m0 + r) * 1024 + kt + cs;
      unsigned short* dst = buf + rep * 2048 + w * 512;
      gload16(Ah + srcA, dst);
      gload16(Al + srcA, dst + 4096);
    }
    {
      int r = tid >> 2, c = tid & 3;
      int cs = (c ^ ((r >> 1) & 3)) * 8;
      int srcB = (n0 + r) * 1024 + kt + cs;
      unsigned short* dst = buf + 8192 + w * 512;
      gload16(Bqh + srcB, dst);
      gload16(Bql + srcB, dst + 2048);
      gload16(Bkh + srcB, dst + 4096);
      gload16(Bkl + srcB, dst + 6144);
      gload16(Bvh + srcB, dst + 8192);
    }
  };

  floatx4 aq[4][2] = {}, ak[4][2] = {}, av[4][2] = {};
  stage(0, 0);
  __syncthreads();
  int cur = 0;
  for (int kt = 0; kt < 1024; kt += 32){
    if (kt + 32 < 1024) stage(kt + 32, cur ^ 1);
    const unsigned short* buf = lds[cur];
    short8 a_h[4], a_l[4], bq_h[2], bq_l[2], bk_h[2], bk_l[2], bv_h[2];
    #pragma unroll
    for (int ms = 0; ms < 4; ms++){
      int r = wr * 64 + ms * 16 + lr;
      int off = r * 32 + ((lg ^ ((r >> 1) & 3)) * 8);
      a_h[ms] = *(const short8*)(buf + off);
      a_l[ms] = *(const short8*)(buf + 4096 + off);
    }
    #pragma unroll
    for (int ns = 0; ns < 2; ns++){
      int r = wc * 32 + ns * 16 + lr;
      int off = r * 32 + ((lg ^ ((r >> 1) & 3)) * 8);
      bq_h[ns] = *(const short8*)(buf + 8192 + off);
      bq_l[ns] = *(const short8*)(buf + 10240 + off);
      bk_h[ns] = *(const short8*)(buf + 12288 + off);
      bk_l[ns] = *(const short8*)(buf + 14336 + off);
      bv_h[ns] = *(const short8*)(buf + 16384 + off);
    }
    #pragma unroll
    for (int ms = 0; ms < 4; ms++)
      #pragma unroll
      for (int ns = 0; ns < 2; ns++){
        aq[ms][ns] = MFMA(a_h[ms], bq_h[ns], aq[ms][ns], 0, 0, 0);
        aq[ms][ns] = MFMA(a_h[ms], bq_l[ns], aq[ms][ns], 0, 0, 0);
        aq[ms][ns] = MFMA(a_l[ms], bq_h[ns], aq[ms][ns], 0, 0, 0);
        ak[ms][ns] = MFMA(a_h[ms], bk_h[ns], ak[ms][ns], 0, 0, 0);
        ak[ms][ns] = MFMA(a_h[ms], bk_l[ns], ak[ms][ns], 0, 0, 0);
        ak[ms][ns] = MFMA(a_l[ms], bk_h[ns], ak[ms][ns], 0, 0, 0);
        av[ms][ns] = MFMA(a_h[ms], bv_h[ns], av[ms][ns], 0, 0, 0);
      }
    __syncthreads();
    cur ^= 1;
  }
  for (int ms = 0; ms < 4; ms++)
    for (int ns = 0; ns < 2; ns++){
      int mrow = m0 + wr * 64 + ms * 16 + lg * 4;
      int ncol = n0 + wc * 32 + ns * 16 + lr;
      for (int rr = 0; rr < 4; rr++){
        int o = (mrow + rr) * 1024 + ncol;
        float v = aq[ms][ns][rr];
        unsigned short hh = f2bf(v);
        qh_o[o] = hh; ql_o[o] = f2bf(v - bf2f(hh));
        v = ak[ms][ns][rr];
        hh = f2bf(v);
        kh_o[o] = hh; kl_o[o] = f2bf(v - bf2f(hh));
      }
      int tb = m0 + wr * 64;
      int bq = tb >> 10, sg = (tb >> 6) & 15;
      int P0 = ((ms >> 1) << 5) | (lg << 3) | ((ms & 1) << 2);
      ushort4v v4;
      for (int rr = 0; rr < 4; rr++) v4[rr] = f2bf(av[ms][ns][rr]);
      *(ushort4v*)(vt_o + (ncol * 4 + bq) * 1024 + sg * 64 + P0) = v4;
    }
}

// ---------------------------------------------------------------------------
// Plain GEMM (final output projection), R13-proven 3-ring + counted vmcnt.
template<int OUT>
__global__ __launch_bounds__(256) void k_gemm(
    const unsigned short* __restrict__ Ah, const unsigned short* __restrict__ Bh,
    void* __restrict__ out0, int M, int N, int K){
  constexpr int BUFN = 6144;
  __shared__ unsigned short lds[3 * BUFN];
  int tid = threadIdx.x;
  int w = tid >> 6, l = tid & 63, lg = l >> 4, lr = l & 15;
  int wr = w >> 1, wc = w & 1;
  int n0 = blockIdx.x * 128, m0 = blockIdx.y * 64;

  auto stage = [&](int kt, int bufi){
    unsigned short* buf = lds + bufi * BUFN;
    { int r = tid >> 2, c = tid & 3;
      int src = (m0 + r) * K + kt + (c ^ ((r >> 1) & 3)) * 8;
      gload16(Ah + src, buf + w * 512); }
    for (int rep = 0; rep < 2; rep++){
      int idx = rep * 256 + tid;
      int r = idx >> 2, c = idx & 3;
      int src = (n0 + r) * K + kt + (c ^ ((r >> 1) & 3)) * 8;
      gload16(Bh + src, buf + 2048 + rep * 2048 + w * 512);
    }
  };

  floatx4 acc[2][4] = {};
  int nT = K >> 5;
  stage(0, 0);
  stage(32, 1);
  for (int t = 0; t < nT; ++t){
    if (t == nT - 1) asm volatile("s_waitcnt vmcnt(0)" ::: "memory");
    else             asm volatile("s_waitcnt vmcnt(3)" ::: "memory");
    __builtin_amdgcn_sched_barrier(0);
    __builtin_amdgcn_s_barrier();
    __builtin_amdgcn_sched_barrier(0);
    if (t + 2 < nT) stage((t + 2) * 32, (t + 2) % 3);

    const unsigned short* buf = lds + (t % 3) * BUFN;
    short8 a_h[2], b_h[4];
    #pragma unroll
    for (int ms = 0; ms < 2; ms++){
      int r = wr * 32 + ms * 16 + lr;
      int off = r * 32 + ((lg ^ ((r >> 1) & 3)) * 8);
      a_h[ms] = *(const short8*)(buf + off);
    }
    #pragma unroll
    for (int ns = 0; ns < 4; ns++){
      int r = wc * 64 + ns * 16 + lr;
      int off = r * 32 + ((lg ^ ((r >> 1) & 3)) * 8);
      b_h[ns] = *(const short8*)(buf + 2048 + off);
    }
    #pragma unroll
    for (int ms = 0; ms < 2; ms++)
      #pragma unroll
      for (int ns = 0; ns < 4; ns++)
        acc[ms][ns] = MFMA(a_h[ms], b_h[ns], acc[ms][ns], 0, 0, 0);
  }
  for (int ms = 0; ms < 2; ms++)
    for (int ns = 0; ns < 4; ns++){
      int mrow = m0 + wr * 32 + ms * 16 + lg * 4;
      int ncol = n0 + wc * 64 + ns * 16 + lr;
      for (int rr = 0; rr < 4; rr++){
        float v = acc[ms][ns][rr];
        int o = (mrow + rr) * N + ncol;
        if constexpr (OUT == 2) ((float*)out0)[o] = v;
        else                    ((unsigned short*)out0)[o] = f2bf(v);
      }
    }
}

// ---------------------------------------------------------------------------
// Flash attention, swapped-operand (R13/R19-proven build, byte-identical).
// Grid 1024 = 16 qt x 64 bh, LPT (qt = 15 - gx>>6), QBLK=64, 4 waves.
// Vt layout: [H][hd][B][S_kappa], addr = ((h*64+d)*4 + b)*1024 + s_phys.
__global__ __launch_bounds__(256) void k_attn(
    const unsigned short* __restrict__ Qh, const unsigned short* __restrict__ Ql,
    const unsigned short* __restrict__ Kh, const unsigned short* __restrict__ Kl,
    const unsigned short* __restrict__ Vt, unsigned short* __restrict__ Ob){
  __shared__ unsigned short s_k[2][12288];   // per buf: Kh 4096 | Kl 4096 | V 4096
  int tid = threadIdx.x;
  int w = tid >> 6, l = tid & 63, lg = l >> 4, lr = l & 15;
  int gx = blockIdx.x;
  int bh = gx & 63, qt = 15 - (gx >> 6);     // LPT: heavy first
  int b = bh >> 4, h = bh & 15;
  int q0 = qt * 64;
  int qs = q0 + w * 16;
  int rowb = b * 1024;

  auto stage = [&](int kt, int bufi){
    int k0 = kt * 64;
    unsigned short* buf = s_k[bufi];
    for (int rep = 0; rep < 2; rep++){
      int idx = rep * 256 + tid;
      int r = idx >> 3, c = idx & 7;
      int cs = c ^ (r & 7);
      int srcK = (rowb + k0 + r) * 1024 + h * 64 + cs * 8;
      int srcV = ((h * 64 + r) * 4 + b) * 1024 + k0 + cs * 8;
      unsigned short* dst = buf + rep * 2048 + w * 512;
      gload16(Kh + srcK, dst);
      gload16(Kl + srcK, dst + 4096);
      gload16(Vt + srcV, dst + 8192);
    }
  };

  short8 fqh[2], fql[2];
  for (int ds = 0; ds < 2; ds++){
    int off = (rowb + qs + lr) * 1024 + h * 64 + ds * 32 + lg * 8;
    fqh[ds] = *(const short8*)(Qh + off);
    fql[ds] = *(const short8*)(Ql + off);
  }

  floatx4 oT[4] = {};      // O^T: col q = lr, row d = dsb*16 + 4*lg + rr
  float m_r = -__builtin_inff(), l_r = 0.f;   // per-lane q = qs + lr

  int ntile = qt + 1;
  stage(0, 0);
  __syncthreads();
  int cur = 0;
  for (int kt = 0; kt < ntile; kt++){
    int k0 = kt * 64;
    if (kt + 1 < ntile) stage(kt + 1, cur ^ 1);
    const unsigned short* kb = s_k[cur];

    floatx4 sc[4] = {};
    __builtin_amdgcn_s_setprio(1);
    for (int ds = 0; ds < 2; ds++)
      for (int s = 0; s < 4; s++){
        int r = s * 16 + lr;
        int off = r * 64 + (((ds * 4 + lg) ^ (r & 7)) * 8);
        short8 kh_f = *(const short8*)(kb + off);
        short8 kl_f = *(const short8*)(kb + 4096 + off);
        sc[s] = MFMA(kh_f, fqh[ds], sc[s], 0, 0, 0);
        sc[s] = MFMA(kl_f, fqh[ds], sc[s], 0, 0, 0);
        sc[s] = MFMA(kh_f, fql[ds], sc[s], 0, 0, 0);
      }
    __builtin_amdgcn_s_setprio(0);

    if (kt == ntile - 1){
      #pragma unroll
      for (int s = 0; s < 4; s++)
        #pragma unroll
        for (int rr = 0; rr < 4; rr++)
          if (k0 + s * 16 + 4 * lg + rr > qs + lr) sc[s][rr] = -__builtin_inff();
    }

    float mx = sc[0][0];
    #pragma unroll
    for (int s = 0; s < 4; s++)
      #pragma unroll
      for (int rr = 0; rr < 4; rr++) mx = fmaxf(mx, sc[s][rr]);
    mx = fmaxf(mx, __shfl_xor(mx, 16));
    mx = fmaxf(mx, __shfl_xor(mx, 32));
    float mn = fmaxf(m_r, mx);
    float fac = __expf(m_r - mn);
    m_r = mn;
    float ps = 0.f;
    #pragma unroll
    for (int s = 0; s < 4; s++)
      #pragma unroll
      for (int rr = 0; rr < 4; rr++){
        float p = __expf(sc[s][rr] - mn);
        sc[s][rr] = p;
        ps += p;
      }
    ps += __shfl_xor(ps, 16);
    ps += __shfl_xor(ps, 32);
    l_r = l_r * fac + ps;
    #pragma unroll
    for (int dsb = 0; dsb < 4; dsb++) oT[dsb] *= fac;

    __builtin_amdgcn_s_setprio(1);
    #pragma unroll
    for (int kk = 0; kk < 2; kk++){
      short8 pb;
      #pragma unroll
      for (int j = 0; j < 8; j++)
        pb[j] = (short)f2bf(sc[2 * kk + (j >> 2)][j & 3]);
      #pragma unroll
      for (int dsb = 0; dsb < 4; dsb++){
        int rv = dsb * 16 + lr;
        int offv = rv * 64 + (((kk * 4 + lg) ^ (rv & 7)) * 8);
        short8 vb = *(const short8*)(kb + 8192 + offv);
        oT[dsb] = MFMA(vb, pb, oT[dsb], 0, 0, 0);
      }
    }
    __builtin_amdgcn_s_setprio(0);
    __syncthreads();
    cur ^= 1;
  }

  float inv = 1.f / l_r;
  int base = (rowb + qs + lr) * 1024 + h * 64;
  #pragma unroll
  for (int dsb = 0; dsb < 4; dsb++){
    ushort4v o4;
    #pragma unroll
    for (int rr = 0; rr < 4; rr++) o4[rr] = f2bf(oT[dsb][rr] * inv);
    *(ushort4v*)(Ob + base + dsb * 16 + 4 * lg) = o4;
  }
}

// ---------------------------------------------------------------------------
extern "C" void kernel_launch(void* const* d_in, const int* in_sizes, int n_in,
                              void* d_out, int out_size, void* d_ws, size_t ws_size,
                              hipStream_t stream){
  const float* x  = (const float*)d_in[0];
  const float* Wq = (const float*)d_in[1];
  const float* Wk = (const float*)d_in[2];
  const float* Wv = (const float*)d_in[3];
  const float* Wo = (const float*)d_in[4];
  const float* fr = (const float*)d_in[5];
  const float* pr = (const float*)d_in[6];

  char* ws = (char*)d_ws;
  size_t off = 0;
  auto alloc = [&](size_t bytes) -> char* {
    char* p = ws + off;
    off += (bytes + 255) & ~(size_t)255;
    return p;
  };
  const size_t WB = (size_t)1024 * 1024 * 2;
  unsigned short* wq_h = (unsigned short*)alloc(WB);
  unsigned short* wq_l = (unsigned short*)alloc(WB);
  unsigned short* wk_h = (unsigned short*)alloc(WB);
  unsigned short* wk_l = (unsigned short*)alloc(WB);
  unsigned short* wv_b = (unsigned short*)alloc(WB);
  unsigned short* wo_b = (unsigned short*)alloc(WB);
  const size_t XB = (size_t)4096 * 1024 * 2;
  unsigned short* x_h = (unsigned short*)alloc(XB);
  unsigned short* x_l = (unsigned short*)alloc(XB);
  unsigned short* q_h = (unsigned short*)alloc(XB);
  unsigned short* q_l = (unsigned short*)alloc(XB);
  unsigned short* k_h = (unsigned short*)alloc(XB);
  unsigned short* k_l = (unsigned short*)alloc(XB);
  unsigned short* vt  = (unsigned short*)alloc(XB);   // V^T [H*hd][B*S_kappa]
  unsigned short* o_b = x_l;   // alias: x_l dead after k_qkv

  k_prep<<<5120, 256, 0, stream>>>(fr, pr, x, Wq, Wk, Wv, Wo,
                                   wq_h, wq_l, wk_h, wk_l, wv_b, wo_b,
                                   x_h, x_l);
  k_qkv<<<512, 256, 0, stream>>>(x_h, x_l, wq_h, wq_l, wk_h, wk_l, wv_b,
                                 q_h, q_l, k_h, k_l, vt);
  k_attn<<<1024, 256, 0, stream>>>(q_h, q_l, k_h, k_l, vt, o_b);
  dim3 ggo(8, 64);
  k_gemm<2><<<ggo, 256, 0, stream>>>(o_b, wo_b, d_out, 4096, 1024, 1024);
}